// Round 13
// baseline (94.724 us; speedup 1.0000x reference)
//
#include <hip/hip_runtime.h>
#include <math.h>

// ---------------------------------------------------------------------------
// FluxAnomalyPredictionTF: F=3, E=6, H=3, d=2, FF=2048, N=16, T=2046, S=W=1024
// R13 = R12 (74.8us) +
//   ff:  T=16 tokens/lane (8 f32x2 pairs), ss=8 row-subslices, 8 iters ->
//        halves LDS wave-instructions (ff was LDS-issue-bound after packing).
//        Word-rotation swizzle (slot=(word+(row>>1))&3) keeps reads
//        conflict-free. launch_bounds(512,2) for ~215 VGPR.
//   frontend: 256 thr; spare wave (lanes 192-255) builds fcc concurrently.
// attn/ffln/final byte-identical to R12.
// ---------------------------------------------------------------------------

#define TL 2046
#define SL 1024

typedef float f32x2 __attribute__((ext_vector_type(2)));

__device__ __forceinline__ float relu_(float a){ return fmaxf(a, 0.f); }
__device__ __forceinline__ float fexp2_(float x){ return __builtin_amdgcn_exp2f(x); }
__device__ __forceinline__ float dpp_xadd1(float x){
  return x + __int_as_float(__builtin_amdgcn_update_dpp(
      0, __float_as_int(x), 0xB1, 0xF, 0xF, true));
}
__device__ __forceinline__ float dpp_xadd2(float x){
  return x + __int_as_float(__builtin_amdgcn_update_dpp(
      0, __float_as_int(x), 0x4E, 0xF, 0xF, true));
}

// ---- VOP3P packed fp32 helpers (gfx90a+).
__device__ __forceinline__ f32x2 pk_fma_blo(f32x2 a, f32x2 b, f32x2 c){
  f32x2 d;
  asm("v_pk_fma_f32 %0, %1, %2, %3 op_sel:[0,0,0] op_sel_hi:[1,0,1]"
      : "=v"(d) : "v"(a), "v"(b), "v"(c));
  return d;
}
__device__ __forceinline__ f32x2 pk_fma_bhi(f32x2 a, f32x2 b, f32x2 c){
  f32x2 d;
  asm("v_pk_fma_f32 %0, %1, %2, %3 op_sel:[0,1,0] op_sel_hi:[1,1,1]"
      : "=v"(d) : "v"(a), "v"(b), "v"(c));
  return d;
}
__device__ __forceinline__ f32x2 pk_fma_blo_clo(f32x2 a, f32x2 b, f32x2 c){
  f32x2 d;
  asm("v_pk_fma_f32 %0, %1, %2, %3 op_sel:[0,0,0] op_sel_hi:[1,0,0]"
      : "=v"(d) : "v"(a), "v"(b), "v"(c));
  return d;
}
__device__ __forceinline__ f32x2 pk_mul_bhi(f32x2 a, f32x2 b){
  f32x2 d;
  asm("v_pk_mul_f32 %0, %1, %2 op_sel:[0,1] op_sel_hi:[1,1]"
      : "=v"(d) : "v"(a), "v"(b));
  return d;
}
__device__ __forceinline__ f32x2 pk_add2(f32x2 a, f32x2 b){
  f32x2 d;
  asm("v_pk_add_f32 %0, %1, %2" : "=v"(d) : "v"(a), "v"(b));
  return d;
}

#define SCQK 1.0201265650432017f  // (1/sqrt(2)) * log2(e)

// ------------------------------ frontend -----------------------------------
// 256 thr: lanes 0-191 = conv path (wave per feature f); lanes 192-255 build
// fcc concurrently (4 items each: 256 blk x 64 x 4 = 65536 exact cover).
__global__ __launch_bounds__(256) void frontend_kernel(
  const float* __restrict__ x, const float* __restrict__ k64,
  const float* __restrict__ b64, const float* __restrict__ k16, const float* __restrict__ b16,
  const float* __restrict__ k8,  const float* __restrict__ b8,
  const float* __restrict__ kw3, const float* __restrict__ bw3,
  const float* __restrict__ km3, const float* __restrict__ bm3,
  const float* __restrict__ kn3, const float* __restrict__ bn3,
  const float* __restrict__ fc1w, const float* __restrict__ fc1b,
  const float* __restrict__ fc2w, const float* __restrict__ fc2b,
  const float* __restrict__ f1w, const float* __restrict__ f1b,
  const float* __restrict__ f2w,
  const float* __restrict__ inw, const float* __restrict__ inb,
  float* __restrict__ fcc, float* __restrict__ seq,
  float4* __restrict__ kv4, float2* __restrict__ qq)
{
  __shared__ float xt[3][200];
  __shared__ float k64s[3*64*8];
  __shared__ float flat_s[64][44];
  __shared__ float h1_s[64][20];
  __shared__ float seq6[64][6];
  const int tid  = threadIdx.x;
  const int f    = (tid >> 6) & 3;
  const int lane = tid & 63;
  const int n    = blockIdx.x >> 4;
  const int s0   = (blockIdx.x & 15) << 6;
  const int s    = s0 + lane;

  if (tid >= 192){
    // fcc[l][j][16]: [0..5]=f1w row j, [6]=f1b[j], [8..13]=f2w[:,j]
    const int base = (blockIdx.x*64 + (tid - 192))*4;
    #pragma unroll
    for (int k = 0; k < 4; k++){
      const int i = base + k;
      const int l = i >> 15, r = i & 32767, j = r >> 4, c = r & 15;
      float v = 0.f;
      if (c < 6)       v = f1w[(l*2048 + j)*6 + c];
      else if (c == 6) v = f1b[l*2048 + j];
      else if (c >= 8 && c < 14) v = f2w[(l*6 + (c-8))*2048 + j];
      fcc[i] = v;
    }
  } else {
    for (int i = tid; i < 600; i += 192){
      int ff = i / 200, pos = i - ff*200;
      int xp = 2*s0 - 39 + pos;
      xt[ff][pos] = (xp >= 0 && xp < TL) ? x[(n*TL + xp)*3 + ff] : 0.f;
    }
    for (int i = tid; i < 1536; i += 192){
      int ff = i >> 9, r = i & 511, t = r >> 3, k = r & 7;
      k64s[i] = k64[k*192 + ff*64 + t];
    }
  }
  __syncthreads();

  if (tid < 192){
    float xr[74];
    {
      const int b = 2*lane;
      #pragma unroll
      for (int i = 0; i < 74; i++) xr[i] = xt[f][b + i];
    }

    // ---- wide: 64-tap ----
    float accw[8], acc_e0, acc_e1;
    #pragma unroll
    for (int k = 0; k < 8; k++) accw[k] = b64[k*3 + f];
    acc_e0 = accw[7]; acc_e1 = accw[0];
    {
      const float* kp = &k64s[f*512];
      #pragma unroll
      for (int t = 0; t < 64; t++){
        float4 wa = *(const float4*)(kp + t*8);
        float4 wb = *(const float4*)(kp + t*8 + 4);
        float xm = xr[8 + t];
        accw[0] = fmaf(xm, wa.x, accw[0]);
        accw[1] = fmaf(xm, wa.y, accw[1]);
        accw[2] = fmaf(xm, wa.z, accw[2]);
        accw[3] = fmaf(xm, wa.w, accw[3]);
        accw[4] = fmaf(xm, wb.x, accw[4]);
        accw[5] = fmaf(xm, wb.y, accw[5]);
        accw[6] = fmaf(xm, wb.z, accw[6]);
        accw[7] = fmaf(xm, wb.w, accw[7]);
        acc_e0 = fmaf(xr[6 + t],  wb.w, acc_e0);
        acc_e1 = fmaf(xr[10 + t], wa.x, acc_e1);
      }
    }
    float yw[10];
    yw[0] = (s > 0) ? 5.f*relu_(acc_e0) : 0.f;
    #pragma unroll
    for (int c = 1; c <= 8; c++) yw[c] = 5.f*relu_(accw[c-1]);
    yw[9] = (s < 1023) ? 5.f*relu_(acc_e1) : 0.f;

    // ---- mid: 16-tap ----
    float w16r[16];
    #pragma unroll
    for (int t = 0; t < 16; t++) w16r[t] = k16[f*16 + t];
    const float bb16 = b16[f];
    float ym[10];
    #pragma unroll
    for (int ci = 0; ci < 10; ci++){
      const int b = (ci == 0) ? 54 : ((ci == 9) ? 2 : 8*(ci-1));
      float a = bb16;
      #pragma unroll
      for (int t = 0; t < 16; t++) a = fmaf(xr[b + t], w16r[t], a);
      ym[ci] = relu_(a);
    }
    if (s == 0)    ym[0] = 0.f;
    if (s == 1023) ym[9] = 0.f;

    // ---- nar: 8-tap, max over 4 ----
    float w8r[8];
    #pragma unroll
    for (int t = 0; t < 8; t++) w8r[t] = k8[f*8 + t];
    const float bb8 = b8[f];
    float yn[10];
    #pragma unroll
    for (int ci = 0; ci < 10; ci++){
      float m = -3.0e38f;
      #pragma unroll
      for (int j2 = 0; j2 < 4; j2++){
        const int b = (ci == 0) ? (58 + 2*j2)
                    : ((ci == 9) ? (6 + 2*j2)
                                 : (4 + 2*(4*(ci-1) + j2)));
        float a = bb8;
        #pragma unroll
        for (int t = 0; t < 8; t++) a = fmaf(xr[b + t], w8r[t], a);
        m = fmaxf(m, a);
      }
      yn[ci] = relu_(m);
    }
    if (s == 0)    yn[0] = 0.f;
    if (s == 1023) yn[9] = 0.f;

    // ---- conv3 + relu + pool2 -> flat ----
    {
      float c0 = kw3[f*3], c1 = kw3[f*3+1], c2 = kw3[f*3+2], bb = bw3[f];
      #pragma unroll
      for (int q = 0; q < 4; q++){
        float z0 = relu_(fmaf(c0, yw[2*q],   fmaf(c1, yw[2*q+1], fmaf(c2, yw[2*q+2], bb))));
        float z1 = relu_(fmaf(c0, yw[2*q+1], fmaf(c1, yw[2*q+2], fmaf(c2, yw[2*q+3], bb))));
        flat_s[lane][q*3 + f] = fmaxf(z0, z1);
      }
    }
    {
      float c0 = km3[f*3], c1 = km3[f*3+1], c2 = km3[f*3+2], bb = bm3[f];
      #pragma unroll
      for (int q = 0; q < 4; q++){
        float z0 = relu_(fmaf(c0, ym[2*q],   fmaf(c1, ym[2*q+1], fmaf(c2, ym[2*q+2], bb))));
        float z1 = relu_(fmaf(c0, ym[2*q+1], fmaf(c1, ym[2*q+2], fmaf(c2, ym[2*q+3], bb))));
        flat_s[lane][12 + q*3 + f] = fmaxf(z0, z1);
      }
    }
    {
      float c0 = kn3[f*3], c1 = kn3[f*3+1], c2 = kn3[f*3+2], bb = bn3[f];
      #pragma unroll
      for (int q = 0; q < 4; q++){
        float z0 = relu_(fmaf(c0, yn[2*q],   fmaf(c1, yn[2*q+1], fmaf(c2, yn[2*q+2], bb))));
        float z1 = relu_(fmaf(c0, yn[2*q+1], fmaf(c1, yn[2*q+2], fmaf(c2, yn[2*q+3], bb))));
        flat_s[lane][24 + q*3 + f] = fmaxf(z0, z1);
      }
    }
  }
  __syncthreads();

  if (tid < 192){
    // ---- fc1 ----
    #pragma unroll
    for (int oi = 0; oi < 6; oi++){
      const int o = 6*f + oi;
      float acc = fc1b[o];
      const float4* wrow = (const float4*)(fc1w + o*36);
      const float4* frow = (const float4*)(&flat_s[lane][0]);
      #pragma unroll
      for (int i = 0; i < 9; i++){
        float4 wv = wrow[i], fv = frow[i];
        acc = fmaf(wv.x, fv.x, acc); acc = fmaf(wv.y, fv.y, acc);
        acc = fmaf(wv.z, fv.z, acc); acc = fmaf(wv.w, fv.w, acc);
      }
      h1_s[lane][o] = relu_(acc);
    }
  }
  __syncthreads();

  if (tid < 192){
    // ---- fc2 ----
    #pragma unroll
    for (int ei = 0; ei < 2; ei++){
      const int e = 2*f + ei;
      float acc = fc2b[e];
      #pragma unroll
      for (int o = 0; o < 18; o++) acc = fmaf(h1_s[lane][o], fc2w[e*18 + o], acc);
      float v = acc < 0.f ? 0.f : acc;
      seq[(n*SL + s)*6 + e] = v;
      seq6[lane][e] = v;
    }
  }
  __syncthreads();

  if (tid < 192){
    // ---- layer-0 qkv ----
    const int g = f;
    float sv[6];
    #pragma unroll
    for (int e = 0; e < 6; e++) sv[e] = seq6[lane][e];
    const int h2 = 2*g;
    float q0 = inb[h2],   q1 = inb[h2+1];
    float k0 = inb[6+h2], k1 = inb[7+h2];
    float v0 = inb[12+h2], v1 = inb[13+h2];
    #pragma unroll
    for (int e = 0; e < 6; e++){
      q0 = fmaf(sv[e], inw[h2*6 + e],      q0);
      q1 = fmaf(sv[e], inw[(h2+1)*6 + e],  q1);
      k0 = fmaf(sv[e], inw[(6+h2)*6 + e],  k0);
      k1 = fmaf(sv[e], inw[(7+h2)*6 + e],  k1);
      v0 = fmaf(sv[e], inw[(12+h2)*6 + e], v0);
      v1 = fmaf(sv[e], inw[(13+h2)*6 + e], v1);
    }
    const int nh = n*3 + g;
    kv4[nh*SL + s] = make_float4(k0*SCQK, k1*SCQK, v0, v1);
    qq [nh*SL + s] = make_float2(q0, q1);
  }
}

// ------------------------------ attention ----------------------------------
// (byte-identical to R12)
__global__ __launch_bounds__(512, 4) void attn_kernel(
  const float4* __restrict__ kv4, const float2* __restrict__ qq,
  float* __restrict__ att_out)
{
  __shared__ float4 sKV[1024];          // 16 KB
  __shared__ float red[8][8][8][3];     // [wave][group][row][val]
  const int tid  = threadIdx.x;
  const int w    = tid >> 6;
  const int lane = tid & 63;
  const int rb   = blockIdx.x << 6;
  const int h    = blockIdx.y;
  const int n    = blockIdx.z;
  const int nh   = n*3 + h;

  const float4* kvp = kv4 + nh*SL;
  sKV[tid]       = kvp[tid];
  sKV[tid + 512] = kvp[tid + 512];

  const int r0 = rb + w*8;
  f32x2 q0p[4], q1p[4];
  {
    const float2* qp = qq + nh*SL + r0;
    #pragma unroll
    for (int p = 0; p < 4; p++){
      float2 qa = qp[2*p], qb = qp[2*p+1];
      q0p[p] = f32x2{qa.x, qb.x};
      q1p[p] = f32x2{qa.y, qb.y};
    }
  }
  __syncthreads();

  f32x2 lvp[4], o0p[4], o1p[4];
  #pragma unroll
  for (int p = 0; p < 4; p++){ lvp[p] = 0.f; o0p[p] = 0.f; o1p[p] = 0.f; }

  #pragma unroll 2
  for (int i = 0; i < 16; i++){
    float4 K = sKV[i*64 + lane];
    f32x2 pA = f32x2{K.x, K.y};
    f32x2 pB = f32x2{K.z, K.w};
    #pragma unroll
    for (int p = 0; p < 4; p++){
      f32x2 sc = pk_fma_blo(q0p[p], pA, pk_mul_bhi(q1p[p], pA));
      f32x2 pe;
      pe.x = fexp2_(sc.x);
      pe.y = fexp2_(sc.y);
      lvp[p] = pk_add2(lvp[p], pe);
      o0p[p] = pk_fma_blo(pe, pB, o0p[p]);
      o1p[p] = pk_fma_bhi(pe, pB, o1p[p]);
    }
  }

  float lv[8], o0[8], o1[8];
  #pragma unroll
  for (int p = 0; p < 4; p++){
    lv[2*p] = lvp[p].x;  lv[2*p+1] = lvp[p].y;
    o0[2*p] = o0p[p].x;  o0[2*p+1] = o0p[p].y;
    o1[2*p] = o1p[p].x;  o1[2*p+1] = o1p[p].y;
  }
  #pragma unroll
  for (int r = 0; r < 8; r++){
    lv[r] = dpp_xadd1(lv[r]); lv[r] = dpp_xadd2(lv[r]); lv[r] += __shfl_xor(lv[r], 4);
    o0[r] = dpp_xadd1(o0[r]); o0[r] = dpp_xadd2(o0[r]); o0[r] += __shfl_xor(o0[r], 4);
    o1[r] = dpp_xadd1(o1[r]); o1[r] = dpp_xadd2(o1[r]); o1[r] += __shfl_xor(o1[r], 4);
  }
  {
    const int g = lane >> 3;
    #pragma unroll
    for (int r = 0; r < 8; r++){
      if ((lane & 7) == r){          // static reg index, predicated store
        red[w][g][r][0] = lv[r];
        red[w][g][r][1] = o0[r];
        red[w][g][r][2] = o1[r];
      }
    }
  }
  __syncthreads();

  if (tid < 64){
    const int ww = tid >> 3, r = tid & 7;
    float L = 0.f, O0 = 0.f, O1 = 0.f;
    #pragma unroll
    for (int g = 0; g < 8; g++){
      L  += red[ww][g][r][0];
      O0 += red[ww][g][r][1];
      O1 += red[ww][g][r][2];
    }
    const float inv = 1.0f / L;
    float* orow = att_out + (n*SL + rb + tid)*6 + 2*h;
    orow[0] = O0*inv; orow[1] = O1*inv;
  }
}

// ------------------- fused oproj+LN1 + FF partial ---------------------------
// grid 512 = 128 token-tiles * 4 j-slices(512 rows); 512 thr = 8 waves.
// T=16 tokens/lane (8 pairs); ss = lane&7 row-subslice; 8 iters/wave.
// Word-rotation swizzle: logical word wd of row r at slot (wd+(r>>1))&3 ->
// 8 rows/iter read 8 distinct 4-bank groups (conflict-free).
__global__ __launch_bounds__(512, 2) void ff_kernel(
  const float* __restrict__ seq_in, const float* __restrict__ att,
  const float* __restrict__ fcc,
  const float* __restrict__ ow, const float* __restrict__ ob,
  const float* __restrict__ l1w, const float* __restrict__ l1b,
  float* __restrict__ seq_mid, float* __restrict__ ffp, int layer)
{
  __shared__ float wc[512][16];  // 32 KB, word-rotated; reduce scratch after
  __shared__ float sM[128][6];
  const int tid   = threadIdx.x;
  const int tile  = blockIdx.x >> 2;
  const int slice = blockIdx.x & 3;
  const int tok0  = tile * 128;

  const float4* FC = (const float4*)(fcc + (size_t)(layer*2048 + slice*512)*16);
  for (int i = tid; i < 2048; i += 512){
    const int row = i >> 2, wd = i & 3;
    ((float4*)wc)[(row << 2) + ((wd + (row >> 1)) & 3)] = FC[i];
  }

  if (tid < 128){
    const int token = tok0 + tid;
    const float* a  = att + token*6;
    const float* W  = ow + layer*36;
    float av[6];
    #pragma unroll
    for (int e = 0; e < 6; e++) av[e] = a[e];
    float y[6]; float mu = 0.f;
    #pragma unroll
    for (int e = 0; e < 6; e++){
      float o = ob[layer*6 + e];
      #pragma unroll
      for (int e2 = 0; e2 < 6; e2++) o = fmaf(av[e2], W[e*6 + e2], o);
      y[e] = seq_in[token*6 + e] + o;
      mu += y[e];
    }
    mu *= (1.f/6.f);
    float var = 0.f;
    #pragma unroll
    for (int e = 0; e < 6; e++){ float d = y[e] - mu; var = fmaf(d, d, var); }
    var *= (1.f/6.f);
    float rstd = rsqrtf(var + 1e-5f);
    #pragma unroll
    for (int e = 0; e < 6; e++)
      sM[tid][e] = (y[e] - mu)*rstd*l1w[layer*6 + e] + l1b[layer*6 + e];
  }
  __syncthreads();

  const int w = tid >> 6, lane = tid & 63, tp = lane >> 3, ss = lane & 7;

  // 16 tokens as 8 pairs
  f32x2 sv2[8][6];
  {
    const float* sp = &sM[tp*16][0];
    #pragma unroll
    for (int p = 0; p < 8; p++)
      #pragma unroll
      for (int e = 0; e < 6; e++)
        sv2[p][e] = f32x2{sp[(2*p)*6 + e], sp[(2*p+1)*6 + e]};
  }
  f32x2 acc2[8][6];
  #pragma unroll
  for (int p = 0; p < 8; p++)
    #pragma unroll
    for (int e = 0; e < 6; e++) acc2[p][e] = 0.f;

  // rows: w*64 + ss + i*8
  #pragma unroll 2
  for (int i = 0; i < 8; i++){
    const int r = (w << 6) + ss + (i << 3);
    const int rot = (r >> 1) & 3;
    const float* rowp = &wc[r][0];
    const f32x2* rw0 = (const f32x2*)(rowp + ((((0 + rot) & 3)) << 2));
    const f32x2* rw1 = (const f32x2*)(rowp + ((((1 + rot) & 3)) << 2));
    const f32x2* rw2 = (const f32x2*)(rowp + ((((2 + rot) & 3)) << 2));
    const f32x2* rw3 = (const f32x2*)(rowp + ((((3 + rot) & 3)) << 2));
    f32x2 p0 = rw0[0], p1 = rw0[1];           // w0,w1 | w2,w3
    f32x2 p2 = rw1[0], p3 = rw1[1];           // w4,w5 | bias,pad
    f32x2 p4 = rw2[0], p5 = rw2[1];           // u0,u1 | u2,u3
    f32x2 p6 = rw3[0];                        // u4,u5
    #pragma unroll
    for (int p = 0; p < 8; p++){
      f32x2 h = pk_fma_blo_clo(sv2[p][0], p0, p3);  // sv0*w0 + bias
      h = pk_fma_bhi(sv2[p][1], p0, h);
      h = pk_fma_blo(sv2[p][2], p1, h);
      h = pk_fma_bhi(sv2[p][3], p1, h);
      h = pk_fma_blo(sv2[p][4], p2, h);
      h = pk_fma_bhi(sv2[p][5], p2, h);
      h.x = fmaxf(h.x, 0.f);
      h.y = fmaxf(h.y, 0.f);
      acc2[p][0] = pk_fma_blo(h, p4, acc2[p][0]);
      acc2[p][1] = pk_fma_bhi(h, p4, acc2[p][1]);
      acc2[p][2] = pk_fma_blo(h, p5, acc2[p][2]);
      acc2[p][3] = pk_fma_bhi(h, p5, acc2[p][3]);
      acc2[p][4] = pk_fma_blo(h, p6, acc2[p][4]);
      acc2[p][5] = pk_fma_bhi(h, p6, acc2[p][5]);
    }
  }

  // unpack pairs -> per-token scalars (16 tokens)
  float acc[16][6];
  #pragma unroll
  for (int p = 0; p < 8; p++)
    #pragma unroll
    for (int e = 0; e < 6; e++){
      acc[2*p][e]   = acc2[p][e].x;
      acc[2*p+1][e] = acc2[p][e].y;
    }

  // reduce across ss (lane bits 0-2): dpp xor1, dpp xor2, shfl xor4
  #pragma unroll
  for (int t = 0; t < 16; t++)
    #pragma unroll
    for (int e = 0; e < 6; e++){
      acc[t][e] = dpp_xadd1(acc[t][e]);
      acc[t][e] = dpp_xadd2(acc[t][e]);
      acc[t][e] += __shfl_xor(acc[t][e], 4);
    }
  __syncthreads();   // all waves done reading wc; reuse as reduce scratch
  float* red = (float*)wc;   // [8 waves][8 tp][96] = 6144 floats <= 8192
  if (ss == 0){
    #pragma unroll
    for (int t = 0; t < 16; t++)
      #pragma unroll
      for (int e = 0; e < 6; e++) red[(w*8 + tp)*96 + t*6 + e] = acc[t][e];
  }
  __syncthreads();
  for (int i = tid; i < 768; i += 512){
    const int tl = i / 6, e = i - tl*6;
    const int rtp = tl >> 4, rt = tl & 15;
    float sum = 0.f;
    #pragma unroll
    for (int wv = 0; wv < 8; wv++)
      sum += red[(wv*8 + rtp)*96 + rt*6 + e];
    ffp[(size_t)(slice*16384 + tok0 + tl)*6 + e] = sum;
  }
  if (slice == 0 && tid < 128){
    #pragma unroll
    for (int e = 0; e < 6; e++) seq_mid[(tok0 + tid)*6 + e] = sM[tid][e];
  }
}

// ------------------- FF-sum + LN2 + next-layer qkv --------------------------
__global__ __launch_bounds__(128) void ffln_kernel(
  const float* __restrict__ seq_mid, const float* __restrict__ ffp,
  const float* __restrict__ f2b, const float* __restrict__ lw,
  const float* __restrict__ lb,
  const float* __restrict__ Wq, const float* __restrict__ Bq,
  float* __restrict__ seq_out, float4* __restrict__ kv4, float2* __restrict__ qq)
{
  const int tok = blockIdx.x*128 + threadIdx.x;
  float y[6]; float mu = 0.f;
  #pragma unroll
  for (int e = 0; e < 6; e++){
    float v = seq_mid[tok*6 + e] + f2b[e];
    v += ffp[(size_t)(0*16384 + tok)*6 + e];
    v += ffp[(size_t)(1*16384 + tok)*6 + e];
    v += ffp[(size_t)(2*16384 + tok)*6 + e];
    v += ffp[(size_t)(3*16384 + tok)*6 + e];
    y[e] = v; mu += v;
  }
  mu *= (1.f/6.f);
  float var = 0.f;
  #pragma unroll
  for (int e = 0; e < 6; e++){ float d = y[e] - mu; var = fmaf(d, d, var); }
  var *= (1.f/6.f);
  float rstd = rsqrtf(var + 1e-5f);
  float sv[6];
  #pragma unroll
  for (int e = 0; e < 6; e++){
    sv[e] = (y[e] - mu)*rstd*lw[e] + lb[e];
    seq_out[tok*6 + e] = sv[e];
  }

  const int n = tok >> 10, t = tok & 1023;
  #pragma unroll
  for (int g = 0; g < 3; g++){
    const int h2 = 2*g;
    float q0 = Bq[h2],   q1 = Bq[h2+1];
    float k0 = Bq[6+h2], k1 = Bq[7+h2];
    float v0 = Bq[12+h2], v1 = Bq[13+h2];
    #pragma unroll
    for (int e = 0; e < 6; e++){
      q0 = fmaf(sv[e], Wq[h2*6 + e],      q0);
      q1 = fmaf(sv[e], Wq[(h2+1)*6 + e],  q1);
      k0 = fmaf(sv[e], Wq[(6+h2)*6 + e],  k0);
      k1 = fmaf(sv[e], Wq[(7+h2)*6 + e],  k1);
      v0 = fmaf(sv[e], Wq[(12+h2)*6 + e], v0);
      v1 = fmaf(sv[e], Wq[(13+h2)*6 + e], v1);
    }
    const int nh = n*3 + g;
    kv4[nh*SL + t] = make_float4(k0*SCQK, k1*SCQK, v0, v1);
    qq [nh*SL + t] = make_float2(q0, q1);
  }
}

// --------------------- head (+ layer-1 FF-sum + LN2) -------------------------
__global__ __launch_bounds__(256) void final_kernel(
  const float* __restrict__ seq_mid, const float* __restrict__ ffp,
  const float* __restrict__ f2b, const float* __restrict__ lw,
  const float* __restrict__ lb,
  const float* __restrict__ o1w, const float* __restrict__ o1b,
  const float* __restrict__ o2w, float* __restrict__ out)
{
  __shared__ float fred[4][6];
  __shared__ float pooled[6];
  const int n = blockIdx.x, tid = threadIdx.x;
  float psum[6] = {0,0,0,0,0,0};

  #pragma unroll
  for (int i = 0; i < 4; i++){
    const int tok = n*SL + tid + i*256;
    float y[6]; float mu = 0.f;
    #pragma unroll
    for (int e = 0; e < 6; e++){
      float v = seq_mid[tok*6 + e] + f2b[e];
      v += ffp[(size_t)(0*16384 + tok)*6 + e];
      v += ffp[(size_t)(1*16384 + tok)*6 + e];
      v += ffp[(size_t)(2*16384 + tok)*6 + e];
      v += ffp[(size_t)(3*16384 + tok)*6 + e];
      y[e] = v; mu += v;
    }
    mu *= (1.f/6.f);
    float var = 0.f;
    #pragma unroll
    for (int e = 0; e < 6; e++){ float d = y[e] - mu; var = fmaf(d, d, var); }
    var *= (1.f/6.f);
    float rstd = rsqrtf(var + 1e-5f);
    #pragma unroll
    for (int e = 0; e < 6; e++)
      psum[e] += (y[e] - mu)*rstd*lw[e] + lb[e];
  }

  #pragma unroll
  for (int e = 0; e < 6; e++){
    psum[e] += __shfl_xor(psum[e], 1);  psum[e] += __shfl_xor(psum[e], 2);
    psum[e] += __shfl_xor(psum[e], 4);  psum[e] += __shfl_xor(psum[e], 8);
    psum[e] += __shfl_xor(psum[e], 16); psum[e] += __shfl_xor(psum[e], 32);
  }
  if ((tid & 63) == 0){
    #pragma unroll
    for (int e = 0; e < 6; e++) fred[tid >> 6][e] = psum[e];
  }
  __syncthreads();
  if (tid < 6){
    float t = fred[0][tid] + fred[1][tid] + fred[2][tid] + fred[3][tid];
    pooled[tid] = fmaxf(t * (1.f/1024.f), 0.f);
  }
  __syncthreads();
  if (tid == 0){
    float o1[7];
    #pragma unroll
    for (int o = 0; o < 7; o++){
      float a = o1b[o];
      #pragma unroll
      for (int e2 = 0; e2 < 6; e2++) a = fmaf(pooled[e2], o1w[o*6 + e2], a);
      o1[o] = relu_(a);
    }
    float lg[4];
    #pragma unroll
    for (int c = 0; c < 4; c++){
      float a = 0.f;
      #pragma unroll
      for (int o = 0; o < 7; o++) a = fmaf(o1[o], o2w[c*7 + o], a);
      lg[c] = a;
    }
    float m = fmaxf(fmaxf(lg[0], lg[1]), fmaxf(lg[2], lg[3]));
    float sum = 0.f;
    #pragma unroll
    for (int c = 0; c < 4; c++) sum += expf(lg[c] - m);
    float lse = m + logf(sum);
    #pragma unroll
    for (int c = 0; c < 4; c++) out[n*4 + c] = lg[c] - lse;
  }
}

// ------------------------------- launch --------------------------------------
extern "C" void kernel_launch(void* const* d_in, const int* in_sizes, int n_in,
                              void* d_out, int out_size, void* d_ws, size_t ws_size,
                              hipStream_t stream)
{
  const float* x    = (const float*)d_in[0];
  const float* k64  = (const float*)d_in[1];
  const float* b64  = (const float*)d_in[2];
  const float* k16  = (const float*)d_in[3];
  const float* b16  = (const float*)d_in[4];
  const float* k8   = (const float*)d_in[5];
  const float* b8   = (const float*)d_in[6];
  const float* kw3  = (const float*)d_in[7];
  const float* bw3  = (const float*)d_in[8];
  const float* km3  = (const float*)d_in[9];
  const float* bm3  = (const float*)d_in[10];
  const float* kn3  = (const float*)d_in[11];
  const float* bn3  = (const float*)d_in[12];
  const float* fc1w = (const float*)d_in[13];
  const float* fc1b = (const float*)d_in[14];
  const float* fc2w = (const float*)d_in[15];
  const float* fc2b = (const float*)d_in[16];
  const float* inw  = (const float*)d_in[17];
  const float* inb  = (const float*)d_in[18];
  const float* ow   = (const float*)d_in[19];
  const float* ob   = (const float*)d_in[20];
  const float* l1w  = (const float*)d_in[21];
  const float* l1b  = (const float*)d_in[22];
  const float* l2w  = (const float*)d_in[23];
  const float* l2b  = (const float*)d_in[24];
  const float* f1w  = (const float*)d_in[25];
  const float* f1b  = (const float*)d_in[26];
  const float* f2w  = (const float*)d_in[27];
  const float* f2b  = (const float*)d_in[28];
  const float* o1w  = (const float*)d_in[29];
  const float* o1b  = (const float*)d_in[30];
  const float* o2w  = (const float*)d_in[31];
  float* out = (float*)d_out;

  float* w = (float*)d_ws;
  float*  seq_a   = w;                       // 98304
  float*  seq_b   = w + 98304;               // 98304
  float*  att     = w + 196608;              // 98304
  float*  seq_mid = w + 294912;              // 98304
  float*  ffp     = w + 393216;              // 393216
  float*  fcc     = w + 786432;              // 65536
  float4* kv4     = (float4*)(w + 851968);   // 196608 floats
  float2* qq      = (float2*)(w + 1048576);  // 98304 floats
  // total 1146880 floats ~= 4.6 MB

  frontend_kernel<<<256, 256, 0, stream>>>(x, k64, b64, k16, b16, k8, b8,
      kw3, bw3, km3, bm3, kn3, bn3, fc1w, fc1b, fc2w, fc2b,
      f1w, f1b, f2w, inw, inb, fcc, seq_a, kv4, qq);

  dim3 agrid(16, 3, 16);
  attn_kernel<<<agrid, 512, 0, stream>>>(kv4, qq, att);
  ff_kernel<<<512, 512, 0, stream>>>(seq_a, att, fcc, ow, ob, l1w, l1b,
      seq_mid, ffp, 0);
  ffln_kernel<<<128, 128, 0, stream>>>(seq_mid, ffp, f2b, l2w, l2b,
      inw + 108, inb + 18, seq_b, kv4, qq);

  attn_kernel<<<agrid, 512, 0, stream>>>(kv4, qq, att);
  ff_kernel<<<512, 512, 0, stream>>>(seq_b, att, fcc, ow, ob, l1w, l1b,
      seq_mid, ffp, 1);
  final_kernel<<<16, 256, 0, stream>>>(seq_mid, ffp, f2b + 6, l2w + 6, l2b + 6,
      o1w, o1b, o2w, out);
}

// Round 14
// 74.555 us; speedup vs baseline: 1.2705x; 1.2705x over previous
//
#include <hip/hip_runtime.h>
#include <math.h>

// ---------------------------------------------------------------------------
// FluxAnomalyPredictionTF: F=3, E=6, H=3, d=2, FF=2048, N=16, T=2046, S=W=1024
// R14 = exact revert to R12 (best measured: 74.76 us).
// R13's ff T=16 hit the VGPR/occupancy cliff (launch_bounds(512,2), ~200 VGPR
// -> 2 waves/SIMD + spills): 94.7us. Reverted per post-mortem discipline.
// Structure: 7 dispatches; attn/ff 512thr with DPP reduces; packed-fp32
// (v_pk_fma_f32 VOP3P) inner loops in attn+ff; bitwise-identical math.
// ---------------------------------------------------------------------------

#define TL 2046
#define SL 1024

typedef float f32x2 __attribute__((ext_vector_type(2)));

__device__ __forceinline__ float relu_(float a){ return fmaxf(a, 0.f); }
__device__ __forceinline__ float fexp2_(float x){ return __builtin_amdgcn_exp2f(x); }
__device__ __forceinline__ float dpp_xadd1(float x){
  return x + __int_as_float(__builtin_amdgcn_update_dpp(
      0, __float_as_int(x), 0xB1, 0xF, 0xF, true));
}
__device__ __forceinline__ float dpp_xadd2(float x){
  return x + __int_as_float(__builtin_amdgcn_update_dpp(
      0, __float_as_int(x), 0x4E, 0xF, 0xF, true));
}

// ---- VOP3P packed fp32 helpers (gfx90a+). op_sel broadcasts a 32-bit half
// of a source pair to both result halves.
__device__ __forceinline__ f32x2 pk_fma_blo(f32x2 a, f32x2 b, f32x2 c){
  f32x2 d;
  asm("v_pk_fma_f32 %0, %1, %2, %3 op_sel:[0,0,0] op_sel_hi:[1,0,1]"
      : "=v"(d) : "v"(a), "v"(b), "v"(c));
  return d;
}
__device__ __forceinline__ f32x2 pk_fma_bhi(f32x2 a, f32x2 b, f32x2 c){
  f32x2 d;
  asm("v_pk_fma_f32 %0, %1, %2, %3 op_sel:[0,1,0] op_sel_hi:[1,1,1]"
      : "=v"(d) : "v"(a), "v"(b), "v"(c));
  return d;
}
__device__ __forceinline__ f32x2 pk_fma_blo_clo(f32x2 a, f32x2 b, f32x2 c){
  f32x2 d;
  asm("v_pk_fma_f32 %0, %1, %2, %3 op_sel:[0,0,0] op_sel_hi:[1,0,0]"
      : "=v"(d) : "v"(a), "v"(b), "v"(c));
  return d;
}
__device__ __forceinline__ f32x2 pk_mul_bhi(f32x2 a, f32x2 b){
  f32x2 d;
  asm("v_pk_mul_f32 %0, %1, %2 op_sel:[0,1] op_sel_hi:[1,1]"
      : "=v"(d) : "v"(a), "v"(b));
  return d;
}
__device__ __forceinline__ f32x2 pk_add2(f32x2 a, f32x2 b){
  f32x2 d;
  asm("v_pk_add_f32 %0, %1, %2" : "=v"(d) : "v"(a), "v"(b));
  return d;
}

#define SCQK 1.0201265650432017f  // (1/sqrt(2)) * log2(e)

// ------------------------------ frontend -----------------------------------
__global__ __launch_bounds__(192) void frontend_kernel(
  const float* __restrict__ x, const float* __restrict__ k64,
  const float* __restrict__ b64, const float* __restrict__ k16, const float* __restrict__ b16,
  const float* __restrict__ k8,  const float* __restrict__ b8,
  const float* __restrict__ kw3, const float* __restrict__ bw3,
  const float* __restrict__ km3, const float* __restrict__ bm3,
  const float* __restrict__ kn3, const float* __restrict__ bn3,
  const float* __restrict__ fc1w, const float* __restrict__ fc1b,
  const float* __restrict__ fc2w, const float* __restrict__ fc2b,
  const float* __restrict__ f1w, const float* __restrict__ f1b,
  const float* __restrict__ f2w,
  const float* __restrict__ inw, const float* __restrict__ inb,
  float* __restrict__ fcc, float* __restrict__ seq,
  float4* __restrict__ kv4, float2* __restrict__ qq)
{
  __shared__ float xt[3][200];
  __shared__ float k64s[3*64*8];
  __shared__ float flat_s[64][44];
  __shared__ float h1_s[64][20];
  __shared__ float seq6[64][6];
  const int tid  = threadIdx.x;
  const int f    = tid >> 6;
  const int lane = tid & 63;
  const int n    = blockIdx.x >> 4;
  const int s0   = (blockIdx.x & 15) << 6;
  const int s    = s0 + lane;

  // fcc[l][j][16]: [0..5]=f1w row j, [6]=f1b[j], [8..13]=f2w[:,j]
  for (int i = blockIdx.x*192 + tid; i < 2*2048*16; i += 256*192){
    int l = i >> 15, r = i & 32767, j = r >> 4, c = r & 15;
    float v = 0.f;
    if (c < 6)       v = f1w[(l*2048 + j)*6 + c];
    else if (c == 6) v = f1b[l*2048 + j];
    else if (c >= 8 && c < 14) v = f2w[(l*6 + (c-8))*2048 + j];
    fcc[i] = v;
  }

  for (int i = tid; i < 600; i += 192){
    int ff = i / 200, pos = i - ff*200;
    int xp = 2*s0 - 39 + pos;
    xt[ff][pos] = (xp >= 0 && xp < TL) ? x[(n*TL + xp)*3 + ff] : 0.f;
  }
  for (int i = tid; i < 1536; i += 192){
    int ff = i >> 9, r = i & 511, t = r >> 3, k = r & 7;
    k64s[i] = k64[k*192 + ff*64 + t];
  }
  __syncthreads();

  float xr[74];
  {
    const int b = 2*lane;
    #pragma unroll
    for (int i = 0; i < 74; i++) xr[i] = xt[f][b + i];
  }

  // ---- wide: 64-tap ----
  float accw[8], acc_e0, acc_e1;
  #pragma unroll
  for (int k = 0; k < 8; k++) accw[k] = b64[k*3 + f];
  acc_e0 = accw[7]; acc_e1 = accw[0];
  {
    const float* kp = &k64s[f*512];
    #pragma unroll
    for (int t = 0; t < 64; t++){
      float4 wa = *(const float4*)(kp + t*8);
      float4 wb = *(const float4*)(kp + t*8 + 4);
      float xm = xr[8 + t];
      accw[0] = fmaf(xm, wa.x, accw[0]);
      accw[1] = fmaf(xm, wa.y, accw[1]);
      accw[2] = fmaf(xm, wa.z, accw[2]);
      accw[3] = fmaf(xm, wa.w, accw[3]);
      accw[4] = fmaf(xm, wb.x, accw[4]);
      accw[5] = fmaf(xm, wb.y, accw[5]);
      accw[6] = fmaf(xm, wb.z, accw[6]);
      accw[7] = fmaf(xm, wb.w, accw[7]);
      acc_e0 = fmaf(xr[6 + t],  wb.w, acc_e0);
      acc_e1 = fmaf(xr[10 + t], wa.x, acc_e1);
    }
  }
  float yw[10];
  yw[0] = (s > 0) ? 5.f*relu_(acc_e0) : 0.f;
  #pragma unroll
  for (int c = 1; c <= 8; c++) yw[c] = 5.f*relu_(accw[c-1]);
  yw[9] = (s < 1023) ? 5.f*relu_(acc_e1) : 0.f;

  // ---- mid: 16-tap ----
  float w16r[16];
  #pragma unroll
  for (int t = 0; t < 16; t++) w16r[t] = k16[f*16 + t];
  const float bb16 = b16[f];
  float ym[10];
  #pragma unroll
  for (int ci = 0; ci < 10; ci++){
    const int b = (ci == 0) ? 54 : ((ci == 9) ? 2 : 8*(ci-1));
    float a = bb16;
    #pragma unroll
    for (int t = 0; t < 16; t++) a = fmaf(xr[b + t], w16r[t], a);
    ym[ci] = relu_(a);
  }
  if (s == 0)    ym[0] = 0.f;
  if (s == 1023) ym[9] = 0.f;

  // ---- nar: 8-tap, max over 4 ----
  float w8r[8];
  #pragma unroll
  for (int t = 0; t < 8; t++) w8r[t] = k8[f*8 + t];
  const float bb8 = b8[f];
  float yn[10];
  #pragma unroll
  for (int ci = 0; ci < 10; ci++){
    float m = -3.0e38f;
    #pragma unroll
    for (int j2 = 0; j2 < 4; j2++){
      const int b = (ci == 0) ? (58 + 2*j2)
                  : ((ci == 9) ? (6 + 2*j2)
                               : (4 + 2*(4*(ci-1) + j2)));
      float a = bb8;
      #pragma unroll
      for (int t = 0; t < 8; t++) a = fmaf(xr[b + t], w8r[t], a);
      m = fmaxf(m, a);
    }
    yn[ci] = relu_(m);
  }
  if (s == 0)    yn[0] = 0.f;
  if (s == 1023) yn[9] = 0.f;

  // ---- conv3 + relu + pool2 -> flat ----
  {
    float c0 = kw3[f*3], c1 = kw3[f*3+1], c2 = kw3[f*3+2], bb = bw3[f];
    #pragma unroll
    for (int q = 0; q < 4; q++){
      float z0 = relu_(fmaf(c0, yw[2*q],   fmaf(c1, yw[2*q+1], fmaf(c2, yw[2*q+2], bb))));
      float z1 = relu_(fmaf(c0, yw[2*q+1], fmaf(c1, yw[2*q+2], fmaf(c2, yw[2*q+3], bb))));
      flat_s[lane][q*3 + f] = fmaxf(z0, z1);
    }
  }
  {
    float c0 = km3[f*3], c1 = km3[f*3+1], c2 = km3[f*3+2], bb = bm3[f];
    #pragma unroll
    for (int q = 0; q < 4; q++){
      float z0 = relu_(fmaf(c0, ym[2*q],   fmaf(c1, ym[2*q+1], fmaf(c2, ym[2*q+2], bb))));
      float z1 = relu_(fmaf(c0, ym[2*q+1], fmaf(c1, ym[2*q+2], fmaf(c2, ym[2*q+3], bb))));
      flat_s[lane][12 + q*3 + f] = fmaxf(z0, z1);
    }
  }
  {
    float c0 = kn3[f*3], c1 = kn3[f*3+1], c2 = kn3[f*3+2], bb = bn3[f];
    #pragma unroll
    for (int q = 0; q < 4; q++){
      float z0 = relu_(fmaf(c0, yn[2*q],   fmaf(c1, yn[2*q+1], fmaf(c2, yn[2*q+2], bb))));
      float z1 = relu_(fmaf(c0, yn[2*q+1], fmaf(c1, yn[2*q+2], fmaf(c2, yn[2*q+3], bb))));
      flat_s[lane][24 + q*3 + f] = fmaxf(z0, z1);
    }
  }
  __syncthreads();

  // ---- fc1 ----
  #pragma unroll
  for (int oi = 0; oi < 6; oi++){
    const int o = 6*f + oi;
    float acc = fc1b[o];
    const float4* wrow = (const float4*)(fc1w + o*36);
    const float4* frow = (const float4*)(&flat_s[lane][0]);
    #pragma unroll
    for (int i = 0; i < 9; i++){
      float4 wv = wrow[i], fv = frow[i];
      acc = fmaf(wv.x, fv.x, acc); acc = fmaf(wv.y, fv.y, acc);
      acc = fmaf(wv.z, fv.z, acc); acc = fmaf(wv.w, fv.w, acc);
    }
    h1_s[lane][o] = relu_(acc);
  }
  __syncthreads();

  // ---- fc2 ----
  #pragma unroll
  for (int ei = 0; ei < 2; ei++){
    const int e = 2*f + ei;
    float acc = fc2b[e];
    #pragma unroll
    for (int o = 0; o < 18; o++) acc = fmaf(h1_s[lane][o], fc2w[e*18 + o], acc);
    float v = acc < 0.f ? 0.f : acc;
    seq[(n*SL + s)*6 + e] = v;
    seq6[lane][e] = v;
  }
  __syncthreads();

  // ---- layer-0 qkv ----
  {
    const int g = f;
    float sv[6];
    #pragma unroll
    for (int e = 0; e < 6; e++) sv[e] = seq6[lane][e];
    const int h2 = 2*g;
    float q0 = inb[h2],   q1 = inb[h2+1];
    float k0 = inb[6+h2], k1 = inb[7+h2];
    float v0 = inb[12+h2], v1 = inb[13+h2];
    #pragma unroll
    for (int e = 0; e < 6; e++){
      q0 = fmaf(sv[e], inw[h2*6 + e],      q0);
      q1 = fmaf(sv[e], inw[(h2+1)*6 + e],  q1);
      k0 = fmaf(sv[e], inw[(6+h2)*6 + e],  k0);
      k1 = fmaf(sv[e], inw[(7+h2)*6 + e],  k1);
      v0 = fmaf(sv[e], inw[(12+h2)*6 + e], v0);
      v1 = fmaf(sv[e], inw[(13+h2)*6 + e], v1);
    }
    const int nh = n*3 + g;
    kv4[nh*SL + s] = make_float4(k0*SCQK, k1*SCQK, v0, v1);
    qq [nh*SL + s] = make_float2(q0, q1);
  }
}

// ------------------------------ attention ----------------------------------
// grid (16 rb(64 rows), 3 h, 16 n); 512 thr = 8 waves -> 24 waves/CU.
// Rows packed pairwise for VOP3P; exp scalar per half; DPP+shfl reduce.
__global__ __launch_bounds__(512, 4) void attn_kernel(
  const float4* __restrict__ kv4, const float2* __restrict__ qq,
  float* __restrict__ att_out)
{
  __shared__ float4 sKV[1024];          // 16 KB
  __shared__ float red[8][8][8][3];     // [wave][group][row][val]
  const int tid  = threadIdx.x;
  const int w    = tid >> 6;
  const int lane = tid & 63;
  const int rb   = blockIdx.x << 6;
  const int h    = blockIdx.y;
  const int n    = blockIdx.z;
  const int nh   = n*3 + h;

  const float4* kvp = kv4 + nh*SL;
  sKV[tid]       = kvp[tid];
  sKV[tid + 512] = kvp[tid + 512];

  const int r0 = rb + w*8;
  f32x2 q0p[4], q1p[4];
  {
    const float2* qp = qq + nh*SL + r0;
    #pragma unroll
    for (int p = 0; p < 4; p++){
      float2 qa = qp[2*p], qb = qp[2*p+1];
      q0p[p] = f32x2{qa.x, qb.x};
      q1p[p] = f32x2{qa.y, qb.y};
    }
  }
  __syncthreads();

  f32x2 lvp[4], o0p[4], o1p[4];
  #pragma unroll
  for (int p = 0; p < 4; p++){ lvp[p] = 0.f; o0p[p] = 0.f; o1p[p] = 0.f; }

  #pragma unroll 2
  for (int i = 0; i < 16; i++){
    float4 K = sKV[i*64 + lane];
    f32x2 pA = f32x2{K.x, K.y};
    f32x2 pB = f32x2{K.z, K.w};
    #pragma unroll
    for (int p = 0; p < 4; p++){
      f32x2 sc = pk_fma_blo(q0p[p], pA, pk_mul_bhi(q1p[p], pA));
      f32x2 pe;
      pe.x = fexp2_(sc.x);
      pe.y = fexp2_(sc.y);
      lvp[p] = pk_add2(lvp[p], pe);
      o0p[p] = pk_fma_blo(pe, pB, o0p[p]);
      o1p[p] = pk_fma_bhi(pe, pB, o1p[p]);
    }
  }

  // unpack pairs -> per-row scalars, then reduce
  float lv[8], o0[8], o1[8];
  #pragma unroll
  for (int p = 0; p < 4; p++){
    lv[2*p] = lvp[p].x;  lv[2*p+1] = lvp[p].y;
    o0[2*p] = o0p[p].x;  o0[2*p+1] = o0p[p].y;
    o1[2*p] = o1p[p].x;  o1[2*p+1] = o1p[p].y;
  }
  #pragma unroll
  for (int r = 0; r < 8; r++){
    lv[r] = dpp_xadd1(lv[r]); lv[r] = dpp_xadd2(lv[r]); lv[r] += __shfl_xor(lv[r], 4);
    o0[r] = dpp_xadd1(o0[r]); o0[r] = dpp_xadd2(o0[r]); o0[r] += __shfl_xor(o0[r], 4);
    o1[r] = dpp_xadd1(o1[r]); o1[r] = dpp_xadd2(o1[r]); o1[r] += __shfl_xor(o1[r], 4);
  }
  {
    const int g = lane >> 3;
    #pragma unroll
    for (int r = 0; r < 8; r++){
      if ((lane & 7) == r){          // static reg index, predicated store
        red[w][g][r][0] = lv[r];
        red[w][g][r][1] = o0[r];
        red[w][g][r][2] = o1[r];
      }
    }
  }
  __syncthreads();

  if (tid < 64){
    const int ww = tid >> 3, r = tid & 7;
    float L = 0.f, O0 = 0.f, O1 = 0.f;
    #pragma unroll
    for (int g = 0; g < 8; g++){
      L  += red[ww][g][r][0];
      O0 += red[ww][g][r][1];
      O1 += red[ww][g][r][2];
    }
    const float inv = 1.0f / L;
    float* orow = att_out + (n*SL + rb + tid)*6 + 2*h;
    orow[0] = O0*inv; orow[1] = O1*inv;
  }
}

// ------------------- fused oproj+LN1 + FF partial ---------------------------
// grid 512 = 128 token-tiles * 4 j-slices(512 rows); 512 thr = 8 waves.
// Tokens packed pairwise; weights broadcast via op_sel from LDS pairs.
__global__ __launch_bounds__(512, 4) void ff_kernel(
  const float* __restrict__ seq_in, const float* __restrict__ att,
  const float* __restrict__ fcc,
  const float* __restrict__ ow, const float* __restrict__ ob,
  const float* __restrict__ l1w, const float* __restrict__ l1b,
  float* __restrict__ seq_mid, float* __restrict__ ffp, int layer)
{
  __shared__ float wc[512][16];  // 32 KB; aliased as reduce scratch after use
  __shared__ float sM[128][6];
  const int tid   = threadIdx.x;
  const int tile  = blockIdx.x >> 2;
  const int slice = blockIdx.x & 3;
  const int tok0  = tile * 128;

  const float4* FC = (const float4*)(fcc + (size_t)(layer*2048 + slice*512)*16);
  for (int i = tid; i < 2048; i += 512)
    ((float4*)wc)[i] = FC[i];

  if (tid < 128){
    const int token = tok0 + tid;
    const float* a  = att + token*6;
    const float* W  = ow + layer*36;
    float av[6];
    #pragma unroll
    for (int e = 0; e < 6; e++) av[e] = a[e];
    float y[6]; float mu = 0.f;
    #pragma unroll
    for (int e = 0; e < 6; e++){
      float o = ob[layer*6 + e];
      #pragma unroll
      for (int e2 = 0; e2 < 6; e2++) o = fmaf(av[e2], W[e*6 + e2], o);
      y[e] = seq_in[token*6 + e] + o;
      mu += y[e];
    }
    mu *= (1.f/6.f);
    float var = 0.f;
    #pragma unroll
    for (int e = 0; e < 6; e++){ float d = y[e] - mu; var = fmaf(d, d, var); }
    var *= (1.f/6.f);
    float rstd = rsqrtf(var + 1e-5f);
    #pragma unroll
    for (int e = 0; e < 6; e++)
      sM[tid][e] = (y[e] - mu)*rstd*l1w[layer*6 + e] + l1b[layer*6 + e];
  }
  __syncthreads();

  const int w = tid >> 6, lane = tid & 63, tp = lane >> 2, ss = lane & 3;

  // token pairs: sv2[p][e] = (sM[tp*8+2p][e], sM[tp*8+2p+1][e])
  f32x2 sv2[4][6];
  {
    const float* sp = &sM[tp*8][0];
    #pragma unroll
    for (int p = 0; p < 4; p++)
      #pragma unroll
      for (int e = 0; e < 6; e++)
        sv2[p][e] = f32x2{sp[(2*p)*6 + e], sp[(2*p+1)*6 + e]};
  }
  f32x2 acc2[4][6];
  #pragma unroll
  for (int p = 0; p < 4; p++)
    #pragma unroll
    for (int e = 0; e < 6; e++) acc2[p][e] = 0.f;

  // wave w -> rows [w*64, w*64+64), ss interleaved by 4 (2-way alias = free)
  const int rbase = w*64 + ss;
  #pragma unroll 2
  for (int i = 0; i < 16; i++){
    const f32x2* wr = (const f32x2*)&wc[rbase + i*4][0];
    f32x2 p0 = wr[0], p1 = wr[1], p2 = wr[2], p3 = wr[3];
    f32x2 p4 = wr[4], p5 = wr[5], p6 = wr[6];
    #pragma unroll
    for (int p = 0; p < 4; p++){
      f32x2 h = pk_fma_blo_clo(sv2[p][0], p0, p3);  // sv0*w0 + bias
      h = pk_fma_bhi(sv2[p][1], p0, h);
      h = pk_fma_blo(sv2[p][2], p1, h);
      h = pk_fma_bhi(sv2[p][3], p1, h);
      h = pk_fma_blo(sv2[p][4], p2, h);
      h = pk_fma_bhi(sv2[p][5], p2, h);
      h.x = fmaxf(h.x, 0.f);
      h.y = fmaxf(h.y, 0.f);
      acc2[p][0] = pk_fma_blo(h, p4, acc2[p][0]);
      acc2[p][1] = pk_fma_bhi(h, p4, acc2[p][1]);
      acc2[p][2] = pk_fma_blo(h, p5, acc2[p][2]);
      acc2[p][3] = pk_fma_bhi(h, p5, acc2[p][3]);
      acc2[p][4] = pk_fma_blo(h, p6, acc2[p][4]);
      acc2[p][5] = pk_fma_bhi(h, p6, acc2[p][5]);
    }
  }

  // unpack pairs -> per-token scalars
  float acc[8][6];
  #pragma unroll
  for (int p = 0; p < 4; p++)
    #pragma unroll
    for (int e = 0; e < 6; e++){
      acc[2*p][e]   = acc2[p][e].x;
      acc[2*p+1][e] = acc2[p][e].y;
    }

  // reduce across ss on the VALU pipe (DPP)
  #pragma unroll
  for (int t = 0; t < 8; t++)
    #pragma unroll
    for (int e = 0; e < 6; e++){
      acc[t][e] = dpp_xadd1(acc[t][e]);
      acc[t][e] = dpp_xadd2(acc[t][e]);
    }
  __syncthreads();   // all waves done reading wc; reuse as reduce scratch
  float* red = (float*)wc;   // [8 waves][16 tp][48] = 6144 floats <= 8192
  if (ss == 0){
    #pragma unroll
    for (int t = 0; t < 8; t++)
      #pragma unroll
      for (int e = 0; e < 6; e++) red[(w*16 + tp)*48 + t*6 + e] = acc[t][e];
  }
  __syncthreads();
  for (int i = tid; i < 768; i += 512){
    const int tl = i / 6, e = i - tl*6;
    const int rtp = tl >> 3, rt = tl & 7;
    float sum = 0.f;
    #pragma unroll
    for (int wv = 0; wv < 8; wv++)
      sum += red[(wv*16 + rtp)*48 + rt*6 + e];
    ffp[(size_t)(slice*16384 + tok0 + tl)*6 + e] = sum;
  }
  if (slice == 0 && tid < 128){
    #pragma unroll
    for (int e = 0; e < 6; e++) seq_mid[(tok0 + tid)*6 + e] = sM[tid][e];
  }
}

// ------------------- FF-sum + LN2 + next-layer qkv --------------------------
__global__ __launch_bounds__(128) void ffln_kernel(
  const float* __restrict__ seq_mid, const float* __restrict__ ffp,
  const float* __restrict__ f2b, const float* __restrict__ lw,
  const float* __restrict__ lb,
  const float* __restrict__ Wq, const float* __restrict__ Bq,
  float* __restrict__ seq_out, float4* __restrict__ kv4, float2* __restrict__ qq)
{
  const int tok = blockIdx.x*128 + threadIdx.x;
  float y[6]; float mu = 0.f;
  #pragma unroll
  for (int e = 0; e < 6; e++){
    float v = seq_mid[tok*6 + e] + f2b[e];
    v += ffp[(size_t)(0*16384 + tok)*6 + e];
    v += ffp[(size_t)(1*16384 + tok)*6 + e];
    v += ffp[(size_t)(2*16384 + tok)*6 + e];
    v += ffp[(size_t)(3*16384 + tok)*6 + e];
    y[e] = v; mu += v;
  }
  mu *= (1.f/6.f);
  float var = 0.f;
  #pragma unroll
  for (int e = 0; e < 6; e++){ float d = y[e] - mu; var = fmaf(d, d, var); }
  var *= (1.f/6.f);
  float rstd = rsqrtf(var + 1e-5f);
  float sv[6];
  #pragma unroll
  for (int e = 0; e < 6; e++){
    sv[e] = (y[e] - mu)*rstd*lw[e] + lb[e];
    seq_out[tok*6 + e] = sv[e];
  }

  const int n = tok >> 10, t = tok & 1023;
  #pragma unroll
  for (int g = 0; g < 3; g++){
    const int h2 = 2*g;
    float q0 = Bq[h2],   q1 = Bq[h2+1];
    float k0 = Bq[6+h2], k1 = Bq[7+h2];
    float v0 = Bq[12+h2], v1 = Bq[13+h2];
    #pragma unroll
    for (int e = 0; e < 6; e++){
      q0 = fmaf(sv[e], Wq[h2*6 + e],      q0);
      q1 = fmaf(sv[e], Wq[(h2+1)*6 + e],  q1);
      k0 = fmaf(sv[e], Wq[(6+h2)*6 + e],  k0);
      k1 = fmaf(sv[e], Wq[(7+h2)*6 + e],  k1);
      v0 = fmaf(sv[e], Wq[(12+h2)*6 + e], v0);
      v1 = fmaf(sv[e], Wq[(13+h2)*6 + e], v1);
    }
    const int nh = n*3 + g;
    kv4[nh*SL + t] = make_float4(k0*SCQK, k1*SCQK, v0, v1);
    qq [nh*SL + t] = make_float2(q0, q1);
  }
}

// --------------------- head (+ layer-1 FF-sum + LN2) -------------------------
__global__ __launch_bounds__(256) void final_kernel(
  const float* __restrict__ seq_mid, const float* __restrict__ ffp,
  const float* __restrict__ f2b, const float* __restrict__ lw,
  const float* __restrict__ lb,
  const float* __restrict__ o1w, const float* __restrict__ o1b,
  const float* __restrict__ o2w, float* __restrict__ out)
{
  __shared__ float fred[4][6];
  __shared__ float pooled[6];
  const int n = blockIdx.x, tid = threadIdx.x;
  float psum[6] = {0,0,0,0,0,0};

  #pragma unroll
  for (int i = 0; i < 4; i++){
    const int tok = n*SL + tid + i*256;
    float y[6]; float mu = 0.f;
    #pragma unroll
    for (int e = 0; e < 6; e++){
      float v = seq_mid[tok*6 + e] + f2b[e];
      v += ffp[(size_t)(0*16384 + tok)*6 + e];
      v += ffp[(size_t)(1*16384 + tok)*6 + e];
      v += ffp[(size_t)(2*16384 + tok)*6 + e];
      v += ffp[(size_t)(3*16384 + tok)*6 + e];
      y[e] = v; mu += v;
    }
    mu *= (1.f/6.f);
    float var = 0.f;
    #pragma unroll
    for (int e = 0; e < 6; e++){ float d = y[e] - mu; var = fmaf(d, d, var); }
    var *= (1.f/6.f);
    float rstd = rsqrtf(var + 1e-5f);
    #pragma unroll
    for (int e = 0; e < 6; e++)
      psum[e] += (y[e] - mu)*rstd*lw[e] + lb[e];
  }

  #pragma unroll
  for (int e = 0; e < 6; e++){
    psum[e] += __shfl_xor(psum[e], 1);  psum[e] += __shfl_xor(psum[e], 2);
    psum[e] += __shfl_xor(psum[e], 4);  psum[e] += __shfl_xor(psum[e], 8);
    psum[e] += __shfl_xor(psum[e], 16); psum[e] += __shfl_xor(psum[e], 32);
  }
  if ((tid & 63) == 0){
    #pragma unroll
    for (int e = 0; e < 6; e++) fred[tid >> 6][e] = psum[e];
  }
  __syncthreads();
  if (tid < 6){
    float t = fred[0][tid] + fred[1][tid] + fred[2][tid] + fred[3][tid];
    pooled[tid] = fmaxf(t * (1.f/1024.f), 0.f);
  }
  __syncthreads();
  if (tid == 0){
    float o1[7];
    #pragma unroll
    for (int o = 0; o < 7; o++){
      float a = o1b[o];
      #pragma unroll
      for (int e2 = 0; e2 < 6; e2++) a = fmaf(pooled[e2], o1w[o*6 + e2], a);
      o1[o] = relu_(a);
    }
    float lg[4];
    #pragma unroll
    for (int c = 0; c < 4; c++){
      float a = 0.f;
      #pragma unroll
      for (int o = 0; o < 7; o++) a = fmaf(o1[o], o2w[c*7 + o], a);
      lg[c] = a;
    }
    float m = fmaxf(fmaxf(lg[0], lg[1]), fmaxf(lg[2], lg[3]));
    float sum = 0.f;
    #pragma unroll
    for (int c = 0; c < 4; c++) sum += expf(lg[c] - m);
    float lse = m + logf(sum);
    #pragma unroll
    for (int c = 0; c < 4; c++) out[n*4 + c] = lg[c] - lse;
  }
}

// ------------------------------- launch --------------------------------------
extern "C" void kernel_launch(void* const* d_in, const int* in_sizes, int n_in,
                              void* d_out, int out_size, void* d_ws, size_t ws_size,
                              hipStream_t stream)
{
  const float* x    = (const float*)d_in[0];
  const float* k64  = (const float*)d_in[1];
  const float* b64  = (const float*)d_in[2];
  const float* k16  = (const float*)d_in[3];
  const float* b16  = (const float*)d_in[4];
  const float* k8   = (const float*)d_in[5];
  const float* b8   = (const float*)d_in[6];
  const float* kw3  = (const float*)d_in[7];
  const float* bw3  = (const float*)d_in[8];
  const float* km3  = (const float*)d_in[9];
  const float* bm3  = (const float*)d_in[10];
  const float* kn3  = (const float*)d_in[11];
  const float* bn3  = (const float*)d_in[12];
  const float* fc1w = (const float*)d_in[13];
  const float* fc1b = (const float*)d_in[14];
  const float* fc2w = (const float*)d_in[15];
  const float* fc2b = (const float*)d_in[16];
  const float* inw  = (const float*)d_in[17];
  const float* inb  = (const float*)d_in[18];
  const float* ow   = (const float*)d_in[19];
  const float* ob   = (const float*)d_in[20];
  const float* l1w  = (const float*)d_in[21];
  const float* l1b  = (const float*)d_in[22];
  const float* l2w  = (const float*)d_in[23];
  const float* l2b  = (const float*)d_in[24];
  const float* f1w  = (const float*)d_in[25];
  const float* f1b  = (const float*)d_in[26];
  const float* f2w  = (const float*)d_in[27];
  const float* f2b  = (const float*)d_in[28];
  const float* o1w  = (const float*)d_in[29];
  const float* o1b  = (const float*)d_in[30];
  const float* o2w  = (const float*)d_in[31];
  float* out = (float*)d_out;

  float* w = (float*)d_ws;
  float*  seq_a   = w;                       // 98304
  float*  seq_b   = w + 98304;               // 98304
  float*  att     = w + 196608;              // 98304
  float*  seq_mid = w + 294912;              // 98304
  float*  ffp     = w + 393216;              // 393216
  float*  fcc     = w + 786432;              // 65536
  float4* kv4     = (float4*)(w + 851968);   // 196608 floats
  float2* qq      = (float2*)(w + 1048576);  // 98304 floats
  // total 1146880 floats ~= 4.6 MB

  frontend_kernel<<<256, 192, 0, stream>>>(x, k64, b64, k16, b16, k8, b8,
      kw3, bw3, km3, bm3, kn3, bn3, fc1w, fc1b, fc2w, fc2b,
      f1w, f1b, f2w, inw, inb, fcc, seq_a, kv4, qq);

  dim3 agrid(16, 3, 16);
  attn_kernel<<<agrid, 512, 0, stream>>>(kv4, qq, att);
  ff_kernel<<<512, 512, 0, stream>>>(seq_a, att, fcc, ow, ob, l1w, l1b,
      seq_mid, ffp, 0);
  ffln_kernel<<<128, 128, 0, stream>>>(seq_mid, ffp, f2b, l2w, l2b,
      inw + 108, inb + 18, seq_b, kv4, qq);

  attn_kernel<<<agrid, 512, 0, stream>>>(kv4, qq, att);
  ff_kernel<<<512, 512, 0, stream>>>(seq_b, att, fcc, ow, ob, l1w, l1b,
      seq_mid, ffp, 1);
  final_kernel<<<16, 256, 0, stream>>>(seq_mid, ffp, f2b + 6, l2w + 6, l2b + 6,
      o1w, o1b, o2w, out);
}